// Round 5
// baseline (348.264 us; speedup 1.0000x reference)
//
#include <hip/hip_runtime.h>

// MAF_Extractor R9: DECOMPOSITION PROBE. Identical kernels to R8, but
// mlp_kernel is dispatched TWICE (idempotent: same feat -> same out).
//   dur(R9) - dur(R8=330.0) = mlp_kernel duration, exactly.
// Session model: fixed overhead 213.3 us (R7: 519.9-306.6); R8 kernels
// total ~116.7 us; roofline says gather ~35-40 + mlp ~15-25 = ~60, so
// ~57 us of slack is in ONE of them -- this round determines which.

#define B_   64
#define N_   431
#define C_   256
#define H_   56
#define W_   56
#define HW_  3136
#define PPB  16            // fallback tile
#define NT_  27            // fallback grid
#define PPB2 32            // mlp points per block
#define NT2  14            // ceil(431/32)
#define NPAD (NT2 * PPB2)  // 448

#define Y0S  136           // 128+8 ushorts
#define Y1S  72            // 64+8

typedef __attribute__((ext_vector_type(8))) short short8;
typedef __attribute__((ext_vector_type(4))) float f32x4;

__device__ __forceinline__ ushort f2bf(float f) {
    unsigned u = __float_as_uint(f);
    u += 0x7fffu + ((u >> 16) & 1u);     // RNE
    return (ushort)(u >> 16);
}
__device__ __forceinline__ uint pack2(float lo, float hi) {
    return (uint)f2bf(lo) | ((uint)f2bf(hi) << 16);
}
__device__ __forceinline__ float lo16(uint u) { return __uint_as_float(u << 16); }
__device__ __forceinline__ float hi16(uint u) { return __uint_as_float(u & 0xffff0000u); }

#define WTOT (128 * 256 + 64 * 384 + 16 * 320)   // 62464 bf16 weight elems
#define GB_  (B_ * 64)                            // gather blocks: b x 4-ch groups

// ---------------- gather (+ weight convert) ----------------
__global__ __launch_bounds__(256, 6) void gather_kernel(
    const float* __restrict__ p,      // (B,N,3)
    const float* __restrict__ cam,    // (B,3)
    const float* __restrict__ sfeat,  // (B,C,H,W) fp32
    const float* __restrict__ W0,
    const float* __restrict__ W1,
    const float* __restrict__ W2,
    ushort* __restrict__ feat,        // (B,32,NPAD,8) bf16
    ushort* __restrict__ W0b,         // (128,256)
    ushort* __restrict__ W1b,         // (64,384)
    ushort* __restrict__ W2p)         // (16,320), rows 5..15 zero
{
    const int bx = blockIdx.x;
    if (bx >= GB_) {
        // ---- 8 trailing blocks: weight fp32 -> bf16 ----
        const int t0 = (bx - GB_) * 256 + threadIdx.x;   // 0..2047
        for (int i = t0; i < WTOT; i += 8 * 256) {
            if (i < 128 * 256) {
                W0b[i] = f2bf(W0[i]);
            } else if (i < 128 * 256 + 64 * 384) {
                const int j = i - 128 * 256;
                W1b[j] = f2bf(W1[j]);
            } else {
                const int j = i - (128 * 256 + 64 * 384);
                const int r = j / 320, c = j - r * 320;
                W2p[j] = (r < 5) ? f2bf(W2[r * 320 + c]) : (ushort)0;
            }
        }
        return;
    }

    __shared__ uint plane01[HW_];     // ch c0,c0+1 packed bf16   12544 B
    __shared__ uint plane23[HW_];     // ch c0+2,c0+3             12544 B

    const int b  = bx >> 6;
    const int cg = bx & 63;
    const int c0 = cg * 4;
    const int t  = threadIdx.x;

    // stage 4 channel planes, coalesced float4, packed to bf16 pairs
    {
        const float4* __restrict__ s0 = (const float4*)(sfeat + ((size_t)b * C_ + c0 + 0) * HW_);
        const float4* __restrict__ s1 = (const float4*)(sfeat + ((size_t)b * C_ + c0 + 1) * HW_);
        const float4* __restrict__ s2 = (const float4*)(sfeat + ((size_t)b * C_ + c0 + 2) * HW_);
        const float4* __restrict__ s3 = (const float4*)(sfeat + ((size_t)b * C_ + c0 + 3) * HW_);
        for (int k = t; k < HW_ / 4; k += 256) {
            const float4 a = s0[k], bb = s1[k];
            uint4 u01;
            u01.x = pack2(a.x, bb.x); u01.y = pack2(a.y, bb.y);
            u01.z = pack2(a.z, bb.z); u01.w = pack2(a.w, bb.w);
            *(uint4*)&plane01[k * 4] = u01;
            const float4 c = s2[k], d = s3[k];
            uint4 u23;
            u23.x = pack2(c.x, d.x); u23.y = pack2(c.y, d.y);
            u23.z = pack2(c.z, d.z); u23.w = pack2(c.w, d.w);
            *(uint4*)&plane23[k * 4] = u23;
        }
    }
    __syncthreads();

    // gather: each thread handles points t, t+256 (projection inline)
    const float s  = cam[b * 3 + 0];
    const float tx = cam[b * 3 + 1];
    const float ty = cam[b * 3 + 2];
    // (B,32,NPAD,8): channel-pair row = cg>>1, within-pair offset = (cg&1)*4
    ushort* __restrict__ fdst = feat + ((size_t)b * 32 + (cg >> 1)) * NPAD * 8
                                     + (size_t)(cg & 1) * 4;

    for (int n = t; n < NPAD; n += 256) {
        int   i00 = 0, i10 = 0, i01 = 0, i11 = 0;
        float w00 = 0.f, w10 = 0.f, w01 = 0.f, w11 = 0.f;
        if (n < N_) {
            const float px = p[((size_t)b * N_ + n) * 3 + 0];
            const float py = p[((size_t)b * N_ + n) * 3 + 1];
            const float x = (s * (px + tx) + 1.f) * 0.5f * (float)(W_ - 1);
            const float y = (s * (py + ty) + 1.f) * 0.5f * (float)(H_ - 1);
            const float x0f = floorf(x), y0f = floorf(y);
            const float wx1 = x - x0f, wx0 = 1.f - wx1;
            const float wy1 = y - y0f, wy0 = 1.f - wy1;
            const int ix0 = (int)x0f, iy0 = (int)y0f;
            const int ix1 = ix0 + 1,  iy1 = iy0 + 1;
            const bool vx0 = (ix0 >= 0) & (ix0 <= W_ - 1);
            const bool vx1 = (ix1 >= 0) & (ix1 <= W_ - 1);
            const bool vy0 = (iy0 >= 0) & (iy0 <= H_ - 1);
            const bool vy1 = (iy1 >= 0) & (iy1 <= H_ - 1);
            const int cx0 = min(max(ix0, 0), W_ - 1);
            const int cx1 = min(max(ix1, 0), W_ - 1);
            const int cy0 = min(max(iy0, 0), H_ - 1);
            const int cy1 = min(max(iy1, 0), H_ - 1);
            w00 = (vx0 & vy0) ? wx0 * wy0 : 0.f;
            w10 = (vx1 & vy0) ? wx1 * wy0 : 0.f;
            w01 = (vx0 & vy1) ? wx0 * wy1 : 0.f;
            w11 = (vx1 & vy1) ? wx1 * wy1 : 0.f;
            i00 = cy0 * W_ + cx0;  i10 = cy0 * W_ + cx1;
            i01 = cy1 * W_ + cx0;  i11 = cy1 * W_ + cx1;
        }
        const uint a00 = plane01[i00], a10 = plane01[i10], a01 = plane01[i01], a11 = plane01[i11];
        const uint c00 = plane23[i00], c10 = plane23[i10], c01 = plane23[i01], c11 = plane23[i11];
        const float v0 = w00 * lo16(a00) + w10 * lo16(a10) + w01 * lo16(a01) + w11 * lo16(a11);
        const float v1 = w00 * hi16(a00) + w10 * hi16(a10) + w01 * hi16(a01) + w11 * hi16(a11);
        const float v2 = w00 * lo16(c00) + w10 * lo16(c10) + w01 * lo16(c01) + w11 * lo16(c11);
        const float v3 = w00 * hi16(c00) + w10 * hi16(c10) + w01 * hi16(c01) + w11 * hi16(c11);
        ushort4 r;
        r.x = f2bf(v0); r.y = f2bf(v1); r.z = f2bf(v2); r.w = f2bf(v3);
        *(ushort4*)(fdst + (size_t)n * 8) = r;
    }
}

// ---------------- MLP: 32 points/block, 2 M-tiles, weight-reg reuse --------
__global__ __launch_bounds__(256, 3) void mlp_kernel(
    const ushort* __restrict__ feat,  // (B,32,NPAD,8) bf16
    const ushort* __restrict__ W0b,
    const float* __restrict__ b0,
    const ushort* __restrict__ W1b,
    const float* __restrict__ b1,
    const ushort* __restrict__ W2p,
    const float* __restrict__ b2,
    float* __restrict__ out)          // (B,5,N)
{
    __shared__ ushort y0_s[PPB2 * Y0S];   // 8704 B
    __shared__ ushort y1_s[PPB2 * Y1S];   // 4608 B

    const int tid  = threadIdx.x;
    const int w    = tid >> 6;
    const int l    = tid & 63;
    const int m    = l & 15;
    const int q    = l >> 4;
    const int tile = blockIdx.x;
    const int b    = blockIdx.y;
    const int n0   = tile * PPB2;

    // A-fragments: af0 = point n0+m, af1 = point n0+16+m.
    // af*[ks] = channels 32ks+8q .. +7 : pair row (4ks+q), one uint4 load.
    const ushort* __restrict__ fb = feat + (size_t)b * 32 * NPAD * 8;
    short8 af0[8], af1[8];
    #pragma unroll
    for (int ks = 0; ks < 8; ++ks) {
        const size_t row = (size_t)(4 * ks + q) * NPAD;
        af0[ks] = *(const short8*)(fb + (row + (n0 + m)) * 8);
        af1[ks] = *(const short8*)(fb + (row + (n0 + 16 + m)) * 8);
    }

    // ---- layer0 (128 <- 256): wave w -> output tiles 2w, 2w+1; 2 M-tiles
    {
        f32x4 a00 = {0.f, 0.f, 0.f, 0.f};   // mtile0 x outtile0
        f32x4 a01 = {0.f, 0.f, 0.f, 0.f};   // mtile0 x outtile1
        f32x4 a10 = {0.f, 0.f, 0.f, 0.f};   // mtile1 x outtile0
        f32x4 a11 = {0.f, 0.f, 0.f, 0.f};   // mtile1 x outtile1
        const ushort* __restrict__ wr0 = W0b + ((size_t)(2 * w) * 16 + m) * 256 + 8 * q;
        const ushort* __restrict__ wr1 = wr0 + 16 * 256;
        #pragma unroll
        for (int ks = 0; ks < 8; ++ks) {
            const short8 w0 = *(const short8*)(wr0 + 32 * ks);
            const short8 w1 = *(const short8*)(wr1 + 32 * ks);
            a00 = __builtin_amdgcn_mfma_f32_16x16x32_bf16(af0[ks], w0, a00, 0, 0, 0);
            a01 = __builtin_amdgcn_mfma_f32_16x16x32_bf16(af0[ks], w1, a01, 0, 0, 0);
            a10 = __builtin_amdgcn_mfma_f32_16x16x32_bf16(af1[ks], w0, a10, 0, 0, 0);
            a11 = __builtin_amdgcn_mfma_f32_16x16x32_bf16(af1[ks], w1, a11, 0, 0, 0);
        }
        const int o0 = (2 * w) * 16 + m, o1 = o0 + 16;
        const float bias0 = b0[o0], bias1 = b0[o1];
        #pragma unroll
        for (int r = 0; r < 4; ++r) {
            float v;
            v = a00[r] + bias0; v = (v > 0.f) ? v : 0.01f * v;
            y0_s[(q * 4 + r) * Y0S + o0] = f2bf(v);
            v = a01[r] + bias1; v = (v > 0.f) ? v : 0.01f * v;
            y0_s[(q * 4 + r) * Y0S + o1] = f2bf(v);
            v = a10[r] + bias0; v = (v > 0.f) ? v : 0.01f * v;
            y0_s[(16 + q * 4 + r) * Y0S + o0] = f2bf(v);
            v = a11[r] + bias1; v = (v > 0.f) ? v : 0.01f * v;
            y0_s[(16 + q * 4 + r) * Y0S + o1] = f2bf(v);
        }
    }
    __syncthreads();

    // ---- layer1 (64 <- [128 y0 | 256 feat]): wave w -> output tile w; 2 M-tiles
    {
        f32x4 acc0 = {0.f, 0.f, 0.f, 0.f};
        f32x4 acc1 = {0.f, 0.f, 0.f, 0.f};
        const ushort* __restrict__ wr = W1b + ((size_t)w * 16 + m) * 384 + 8 * q;
        #pragma unroll
        for (int ks = 0; ks < 4; ++ks) {
            const short8 a0 = *(const short8*)(y0_s + m * Y0S + 32 * ks + 8 * q);
            const short8 a1 = *(const short8*)(y0_s + (16 + m) * Y0S + 32 * ks + 8 * q);
            const short8 bb = *(const short8*)(wr + 32 * ks);
            acc0 = __builtin_amdgcn_mfma_f32_16x16x32_bf16(a0, bb, acc0, 0, 0, 0);
            acc1 = __builtin_amdgcn_mfma_f32_16x16x32_bf16(a1, bb, acc1, 0, 0, 0);
        }
        #pragma unroll
        for (int ks = 4; ks < 12; ++ks) {
            const short8 bb = *(const short8*)(wr + 32 * ks);
            acc0 = __builtin_amdgcn_mfma_f32_16x16x32_bf16(af0[ks - 4], bb, acc0, 0, 0, 0);
            acc1 = __builtin_amdgcn_mfma_f32_16x16x32_bf16(af1[ks - 4], bb, acc1, 0, 0, 0);
        }
        const int o = w * 16 + m;
        const float bias = b1[o];
        #pragma unroll
        for (int r = 0; r < 4; ++r) {
            float v;
            v = acc0[r] + bias; v = (v > 0.f) ? v : 0.01f * v;
            y1_s[(q * 4 + r) * Y1S + o] = f2bf(v);
            v = acc1[r] + bias; v = (v > 0.f) ? v : 0.01f * v;
            y1_s[(16 + q * 4 + r) * Y1S + o] = f2bf(v);
        }
    }
    __syncthreads();

    // ---- layer2 (5 <- [64 y1 | 256 feat]): wave 0 -> mtile0, wave 1 -> mtile1
    if (w < 2) {
        const int mt = w;
        f32x4 acc = {0.f, 0.f, 0.f, 0.f};
        const ushort* __restrict__ wr = W2p + (size_t)m * 320 + 8 * q;
        #pragma unroll
        for (int ks = 0; ks < 2; ++ks) {
            const short8 a  = *(const short8*)(y1_s + (mt * 16 + m) * Y1S + 32 * ks + 8 * q);
            const short8 bb = *(const short8*)(wr + 32 * ks);
            acc = __builtin_amdgcn_mfma_f32_16x16x32_bf16(a, bb, acc, 0, 0, 0);
        }
        #pragma unroll
        for (int ks = 2; ks < 10; ++ks) {
            const short8 bb = *(const short8*)(wr + 32 * ks);
            const short8 a  = mt ? af1[ks - 2] : af0[ks - 2];
            acc = __builtin_amdgcn_mfma_f32_16x16x32_bf16(a, bb, acc, 0, 0, 0);
        }
        if (m < 5) {
            const float bias = b2[m];
            #pragma unroll
            for (int r = 0; r < 4; ++r) {
                const int nn = n0 + mt * 16 + q * 4 + r;
                if (nn < N_) {
                    float v = acc[r] + bias;
                    out[((size_t)b * 5 + m) * N_ + nn] = (v > 0.f) ? v : 0.f;
                }
            }
        }
    }
}

// ---------------- fp32 NCHW fallback (ws too small) ----------------
__global__ __launch_bounds__(256, 4) void maf_fallback_kernel(
    const float* __restrict__ p, const float* __restrict__ cam,
    const float* __restrict__ sfeat,
    const float* __restrict__ W0, const float* __restrict__ b0,
    const float* __restrict__ W1, const float* __restrict__ b1,
    const float* __restrict__ W2, const float* __restrict__ b2,
    float* __restrict__ out)
{
    __shared__ float feat_s[PPB][C_ + 4];
    __shared__ float y0_s[PPB][128 + 4];
    __shared__ float y1_s[PPB][64 + 4];

    const int tid = threadIdx.x;
    const int b   = blockIdx.y;
    const int n0  = blockIdx.x * PPB;
    const float s  = cam[b * 3 + 0];
    const float tx = cam[b * 3 + 1];
    const float ty = cam[b * 3 + 2];
    {
        const int c = tid;
        const float* __restrict__ fb = sfeat + ((size_t)b * C_ + c) * HW_;
        for (int pp = 0; pp < PPB; ++pp) {
            const int n = n0 + pp;
            float val = 0.f;
            if (n < N_) {
                const float px = p[((size_t)b * N_ + n) * 3 + 0];
                const float py = p[((size_t)b * N_ + n) * 3 + 1];
                const float x = (s * (px + tx) + 1.f) * 0.5f * (float)(W_ - 1);
                const float y = (s * (py + ty) + 1.f) * 0.5f * (float)(H_ - 1);
                const float x0f = floorf(x), y0f = floorf(y);
                const float wx1 = x - x0f, wx0 = 1.f - wx1;
                const float wy1 = y - y0f, wy0 = 1.f - wy1;
                const int ix0 = (int)x0f, iy0 = (int)y0f;
                const int ix1 = ix0 + 1,  iy1 = iy0 + 1;
                const bool vx0 = (ix0 >= 0) & (ix0 <= W_ - 1);
                const bool vx1 = (ix1 >= 0) & (ix1 <= W_ - 1);
                const bool vy0 = (iy0 >= 0) & (iy0 <= H_ - 1);
                const bool vy1 = (iy1 >= 0) & (iy1 <= H_ - 1);
                const int cx0 = min(max(ix0, 0), W_ - 1);
                const int cx1 = min(max(ix1, 0), W_ - 1);
                const int cy0 = min(max(iy0, 0), H_ - 1);
                const int cy1 = min(max(iy1, 0), H_ - 1);
                const float w00 = (vx0 & vy0) ? wx0 * wy0 : 0.f;
                const float w10 = (vx1 & vy0) ? wx1 * wy0 : 0.f;
                const float w01 = (vx0 & vy1) ? wx0 * wy1 : 0.f;
                const float w11 = (vx1 & vy1) ? wx1 * wy1 : 0.f;
                val = w00 * fb[cy0 * W_ + cx0] + w10 * fb[cy0 * W_ + cx1]
                    + w01 * fb[cy1 * W_ + cx0] + w11 * fb[cy1 * W_ + cx1];
            }
            feat_s[pp][c] = val;
        }
    }
    __syncthreads();
    {
        const int o = tid & 127, pg = tid >> 7, p0 = pg * 8;
        const float* __restrict__ wr = W0 + (size_t)o * 256;
        float acc[8] = {0, 0, 0, 0, 0, 0, 0, 0};
        for (int k = 0; k < 256; k += 4) {
            const float4 w = *(const float4*)(wr + k);
            for (int i = 0; i < 8; ++i) {
                const float4 f = *(const float4*)&feat_s[p0 + i][k];
                acc[i] += w.x * f.x + w.y * f.y + w.z * f.z + w.w * f.w;
            }
        }
        const float bias = b0[o];
        for (int i = 0; i < 8; ++i) {
            const float v = acc[i] + bias;
            y0_s[p0 + i][o] = (v > 0.f) ? v : 0.01f * v;
        }
    }
    __syncthreads();
    {
        const int o = tid & 63, pg = tid >> 6, p0 = pg * 4;
        const float* __restrict__ wr = W1 + (size_t)o * 384;
        float acc[4] = {0, 0, 0, 0};
        for (int k = 0; k < 128; k += 4) {
            const float4 w = *(const float4*)(wr + k);
            for (int i = 0; i < 4; ++i) {
                const float4 f = *(const float4*)&y0_s[p0 + i][k];
                acc[i] += w.x * f.x + w.y * f.y + w.z * f.z + w.w * f.w;
            }
        }
        for (int k = 0; k < 256; k += 4) {
            const float4 w = *(const float4*)(wr + 128 + k);
            for (int i = 0; i < 4; ++i) {
                const float4 f = *(const float4*)&feat_s[p0 + i][k];
                acc[i] += w.x * f.x + w.y * f.y + w.z * f.z + w.w * f.w;
            }
        }
        const float bias = b1[o];
        for (int i = 0; i < 4; ++i) {
            const float v = acc[i] + bias;
            y1_s[p0 + i][o] = (v > 0.f) ? v : 0.01f * v;
        }
    }
    __syncthreads();
    if (tid < 80) {
        const int o = tid >> 4, pp = tid & 15;
        const float* __restrict__ wr = W2 + (size_t)o * 320;
        float acc = 0.f;
        for (int k = 0; k < 64; k += 4) {
            const float4 w = *(const float4*)(wr + k);
            const float4 f = *(const float4*)&y1_s[pp][k];
            acc += w.x * f.x + w.y * f.y + w.z * f.z + w.w * f.w;
        }
        for (int k = 0; k < 256; k += 4) {
            const float4 w = *(const float4*)(wr + 64 + k);
            const float4 f = *(const float4*)&feat_s[pp][k];
            acc += w.x * f.x + w.y * f.y + w.z * f.z + w.w * f.w;
        }
        const int n = n0 + pp;
        if (n < N_) {
            float v = acc + b2[o];
            out[((size_t)b * 5 + o) * N_ + n] = (v > 0.f) ? v : 0.f;
        }
    }
}

extern "C" void kernel_launch(void* const* d_in, const int* in_sizes, int n_in,
                              void* d_out, int out_size, void* d_ws, size_t ws_size,
                              hipStream_t stream) {
    const float* p     = (const float*)d_in[0];
    const float* cam   = (const float*)d_in[1];
    const float* sfeat = (const float*)d_in[2];
    const float* W0    = (const float*)d_in[3];
    const float* b0    = (const float*)d_in[4];
    const float* W1    = (const float*)d_in[5];
    const float* b1    = (const float*)d_in[6];
    const float* W2    = (const float*)d_in[7];
    const float* b2    = (const float*)d_in[8];
    float* out = (float*)d_out;

    const size_t feat_elems = (size_t)B_ * 32 * NPAD * 8;   // 7,340,032 bf16
    size_t off = feat_elems;
    const size_t w0_off = off; off += 128 * 256;
    const size_t w1_off = off; off += 64 * 384;
    const size_t w2_off = off; off += 16 * 320;
    const size_t need = off * sizeof(ushort);               // ~14.9 MB

    if (ws_size >= need) {
        ushort* feat = (ushort*)d_ws;
        ushort* W0b  = feat + w0_off;
        ushort* W1b  = feat + w1_off;
        ushort* W2p  = feat + w2_off;
        gather_kernel<<<GB_ + 8, 256, 0, stream>>>(
            p, cam, sfeat, W0, W1, W2, feat, W0b, W1b, W2p);
        // PROBE: dispatch mlp TWICE (idempotent). dur(R9)-330.0 = mlp time.
        mlp_kernel<<<dim3(NT2, B_), 256, 0, stream>>>(
            feat, W0b, b0, W1b, b1, W2p, b2, out);
        mlp_kernel<<<dim3(NT2, B_), 256, 0, stream>>>(
            feat, W0b, b0, W1b, b1, W2p, b2, out);
    } else {
        maf_fallback_kernel<<<dim3(NT_, B_), 256, 0, stream>>>(
            p, cam, sfeat, W0, b0, W1, b1, W2, b2, out);
    }
}

// Round 7
// 329.287 us; speedup vs baseline: 1.0576x; 1.0576x over previous
//
#include <hip/hip_runtime.h>

// MAF_Extractor R10 (resubmit; Round-6 bench was a container flake -- the
// R2/R3->R4 precedent shows these are uncorrelated with kernel content:
// byte-identical R8 failed twice then passed unchanged).
//
// R10 attacks gather (probe-isolated at ~98 us of ~117 us kernel total;
// mlp = 18.3 us). Diagnosis: staging reads run at ~2.2 TB/s == in-flight
// deficit (Little's law: ~7.7 KB/CU outstanding vs ~40 KB needed) because
// the k-loop drains vmcnt every 2 loads to pack into LDS. Fix: fully-
// unrolled 12x float4 loads into named regs (12 KB/wave in flight), THEN
// pack+store; p-loads hoisted to kernel entry so their latency hides under
// staging; launch_bounds (256,4) for VGPR headroom.
// Predict dur 330 -> ~275-295. Null (>=325) -> gather-x2 counter probe.

#define B_   64
#define N_   431
#define C_   256
#define H_   56
#define W_   56
#define HW_  3136
#define PPB  16            // fallback tile
#define NT_  27            // fallback grid
#define PPB2 32            // mlp points per block
#define NT2  14            // ceil(431/32)
#define NPAD (NT2 * PPB2)  // 448

#define Y0S  136           // 128+8 ushorts
#define Y1S  72            // 64+8

typedef __attribute__((ext_vector_type(8))) short short8;
typedef __attribute__((ext_vector_type(4))) float f32x4;

__device__ __forceinline__ ushort f2bf(float f) {
    unsigned u = __float_as_uint(f);
    u += 0x7fffu + ((u >> 16) & 1u);     // RNE
    return (ushort)(u >> 16);
}
__device__ __forceinline__ uint pack2(float lo, float hi) {
    return (uint)f2bf(lo) | ((uint)f2bf(hi) << 16);
}
__device__ __forceinline__ float lo16(uint u) { return __uint_as_float(u << 16); }
__device__ __forceinline__ float hi16(uint u) { return __uint_as_float(u & 0xffff0000u); }

#define WTOT (128 * 256 + 64 * 384 + 16 * 320)   // 62464 bf16 weight elems
#define GB_  (B_ * 64)                            // gather blocks: b x 4-ch groups

// bilinear sample of packed planes + bf16 store; weights zeroed if !valid
__device__ __forceinline__ void sample_store(
    const uint* __restrict__ plane01, const uint* __restrict__ plane23,
    ushort* __restrict__ fdst, int n, float px, float py,
    float s, float tx, float ty, bool valid)
{
    const float x = (s * (px + tx) + 1.f) * 0.5f * (float)(W_ - 1);
    const float y = (s * (py + ty) + 1.f) * 0.5f * (float)(H_ - 1);
    const float x0f = floorf(x), y0f = floorf(y);
    const float wx1 = x - x0f, wx0 = 1.f - wx1;
    const float wy1 = y - y0f, wy0 = 1.f - wy1;
    const int ix0 = (int)x0f, iy0 = (int)y0f;
    const int ix1 = ix0 + 1,  iy1 = iy0 + 1;
    const bool vx0 = (ix0 >= 0) & (ix0 <= W_ - 1) & valid;
    const bool vx1 = (ix1 >= 0) & (ix1 <= W_ - 1) & valid;
    const bool vy0 = (iy0 >= 0) & (iy0 <= H_ - 1);
    const bool vy1 = (iy1 >= 0) & (iy1 <= H_ - 1);
    const int cx0 = min(max(ix0, 0), W_ - 1);
    const int cx1 = min(max(ix1, 0), W_ - 1);
    const int cy0 = min(max(iy0, 0), H_ - 1);
    const int cy1 = min(max(iy1, 0), H_ - 1);
    const float w00 = (vx0 & vy0) ? wx0 * wy0 : 0.f;
    const float w10 = (vx1 & vy0) ? wx1 * wy0 : 0.f;
    const float w01 = (vx0 & vy1) ? wx0 * wy1 : 0.f;
    const float w11 = (vx1 & vy1) ? wx1 * wy1 : 0.f;
    const int i00 = cy0 * W_ + cx0, i10 = cy0 * W_ + cx1;
    const int i01 = cy1 * W_ + cx0, i11 = cy1 * W_ + cx1;
    const uint a00 = plane01[i00], a10 = plane01[i10], a01 = plane01[i01], a11 = plane01[i11];
    const uint c00 = plane23[i00], c10 = plane23[i10], c01 = plane23[i01], c11 = plane23[i11];
    const float v0 = w00 * lo16(a00) + w10 * lo16(a10) + w01 * lo16(a01) + w11 * lo16(a11);
    const float v1 = w00 * hi16(a00) + w10 * hi16(a10) + w01 * hi16(a01) + w11 * hi16(a11);
    const float v2 = w00 * lo16(c00) + w10 * lo16(c10) + w01 * lo16(c01) + w11 * lo16(c11);
    const float v3 = w00 * hi16(c00) + w10 * hi16(c10) + w01 * hi16(c01) + w11 * hi16(c11);
    ushort4 r;
    r.x = f2bf(v0); r.y = f2bf(v1); r.z = f2bf(v2); r.w = f2bf(v3);
    *(ushort4*)(fdst + (size_t)n * 8) = r;
}

// ---------------- gather (+ weight convert) ----------------
__global__ __launch_bounds__(256, 4) void gather_kernel(
    const float* __restrict__ p,      // (B,N,3)
    const float* __restrict__ cam,    // (B,3)
    const float* __restrict__ sfeat,  // (B,C,H,W) fp32
    const float* __restrict__ W0,
    const float* __restrict__ W1,
    const float* __restrict__ W2,
    ushort* __restrict__ feat,        // (B,32,NPAD,8) bf16
    ushort* __restrict__ W0b,         // (128,256)
    ushort* __restrict__ W1b,         // (64,384)
    ushort* __restrict__ W2p)         // (16,320), rows 5..15 zero
{
    const int bx = blockIdx.x;
    if (bx >= GB_) {
        // ---- 8 trailing blocks: weight fp32 -> bf16 ----
        const int t0 = (bx - GB_) * 256 + threadIdx.x;   // 0..2047
        for (int i = t0; i < WTOT; i += 8 * 256) {
            if (i < 128 * 256) {
                W0b[i] = f2bf(W0[i]);
            } else if (i < 128 * 256 + 64 * 384) {
                const int j = i - 128 * 256;
                W1b[j] = f2bf(W1[j]);
            } else {
                const int j = i - (128 * 256 + 64 * 384);
                const int r = j / 320, c = j - r * 320;
                W2p[j] = (r < 5) ? f2bf(W2[r * 320 + c]) : (ushort)0;
            }
        }
        return;
    }

    __shared__ uint plane01[HW_];     // ch c0,c0+1 packed bf16   12544 B
    __shared__ uint plane23[HW_];     // ch c0+2,c0+3             12544 B

    const int b  = bx >> 6;
    const int cg = bx & 63;
    const int c0 = cg * 4;
    const int t  = threadIdx.x;

    // ---- early: cam + p loads issued NOW, latency hides under staging ----
    const float s  = cam[b * 3 + 0];
    const float tx = cam[b * 3 + 1];
    const float ty = cam[b * 3 + 2];
    const int   nA  = t;                       // always < N_ (256 <= 431)
    const int   nB  = t + 256;                 // valid store iff t < 192
    const int   nBc = min(nB, N_ - 1);         // clamped load index
    const float pxA = p[((size_t)b * N_ + nA)  * 3 + 0];
    const float pyA = p[((size_t)b * N_ + nA)  * 3 + 1];
    const float pxB = p[((size_t)b * N_ + nBc) * 3 + 0];
    const float pyB = p[((size_t)b * N_ + nBc) * 3 + 1];

    // ---- staging: 12 loads in flight (named regs, static idx), then pack ----
    {
        const float4* __restrict__ s0 = (const float4*)(sfeat + ((size_t)b * C_ + c0 + 0) * HW_);
        const float4* __restrict__ s1 = (const float4*)(sfeat + ((size_t)b * C_ + c0 + 1) * HW_);
        const float4* __restrict__ s2 = (const float4*)(sfeat + ((size_t)b * C_ + c0 + 2) * HW_);
        const float4* __restrict__ s3 = (const float4*)(sfeat + ((size_t)b * C_ + c0 + 3) * HW_);
        // HW_/4 = 784 = 3*256 + 16: uniform 3 iters/thread + 16-thread tail.
        const float4 a0 = s0[t],        b0v = s1[t],        c0v = s2[t],        d0 = s3[t];
        const float4 a1 = s0[t + 256],  b1v = s1[t + 256],  c1v = s2[t + 256],  d1 = s3[t + 256];
        const float4 a2 = s0[t + 512],  b2v = s1[t + 512],  c2v = s2[t + 512],  d2 = s3[t + 512];

        uint4 u01, u23;
        u01.x = pack2(a0.x, b0v.x); u01.y = pack2(a0.y, b0v.y);
        u01.z = pack2(a0.z, b0v.z); u01.w = pack2(a0.w, b0v.w);
        u23.x = pack2(c0v.x, d0.x); u23.y = pack2(c0v.y, d0.y);
        u23.z = pack2(c0v.z, d0.z); u23.w = pack2(c0v.w, d0.w);
        *(uint4*)&plane01[t * 4] = u01;
        *(uint4*)&plane23[t * 4] = u23;

        u01.x = pack2(a1.x, b1v.x); u01.y = pack2(a1.y, b1v.y);
        u01.z = pack2(a1.z, b1v.z); u01.w = pack2(a1.w, b1v.w);
        u23.x = pack2(c1v.x, d1.x); u23.y = pack2(c1v.y, d1.y);
        u23.z = pack2(c1v.z, d1.z); u23.w = pack2(c1v.w, d1.w);
        *(uint4*)&plane01[(t + 256) * 4] = u01;
        *(uint4*)&plane23[(t + 256) * 4] = u23;

        u01.x = pack2(a2.x, b2v.x); u01.y = pack2(a2.y, b2v.y);
        u01.z = pack2(a2.z, b2v.z); u01.w = pack2(a2.w, b2v.w);
        u23.x = pack2(c2v.x, d2.x); u23.y = pack2(c2v.y, d2.y);
        u23.z = pack2(c2v.z, d2.z); u23.w = pack2(c2v.w, d2.w);
        *(uint4*)&plane01[(t + 512) * 4] = u01;
        *(uint4*)&plane23[(t + 512) * 4] = u23;

        if (t < 16) {                          // tail: k = 768 + t
            const int k = 768 + t;
            const float4 at = s0[k], bt = s1[k], ct = s2[k], dt = s3[k];
            uint4 w01, w23;
            w01.x = pack2(at.x, bt.x); w01.y = pack2(at.y, bt.y);
            w01.z = pack2(at.z, bt.z); w01.w = pack2(at.w, bt.w);
            w23.x = pack2(ct.x, dt.x); w23.y = pack2(ct.y, dt.y);
            w23.z = pack2(ct.z, dt.z); w23.w = pack2(ct.w, dt.w);
            *(uint4*)&plane01[k * 4] = w01;
            *(uint4*)&plane23[k * 4] = w23;
        }
    }
    __syncthreads();

    // ---- gather: p already in registers; pure LDS + VALU now ----
    // (B,32,NPAD,8): channel-pair row = cg>>1, within-pair offset = (cg&1)*4
    ushort* __restrict__ fdst = feat + ((size_t)b * 32 + (cg >> 1)) * NPAD * 8
                                     + (size_t)(cg & 1) * 4;
    sample_store(plane01, plane23, fdst, nA, pxA, pyA, s, tx, ty, true);
    if (t < 192)
        sample_store(plane01, plane23, fdst, nB, pxB, pyB, s, tx, ty, nB < N_);
}

// ---------------- MLP: 32 points/block, 2 M-tiles, weight-reg reuse --------
__global__ __launch_bounds__(256, 3) void mlp_kernel(
    const ushort* __restrict__ feat,  // (B,32,NPAD,8) bf16
    const ushort* __restrict__ W0b,
    const float* __restrict__ b0,
    const ushort* __restrict__ W1b,
    const float* __restrict__ b1,
    const ushort* __restrict__ W2p,
    const float* __restrict__ b2,
    float* __restrict__ out)          // (B,5,N)
{
    __shared__ ushort y0_s[PPB2 * Y0S];   // 8704 B
    __shared__ ushort y1_s[PPB2 * Y1S];   // 4608 B

    const int tid  = threadIdx.x;
    const int w    = tid >> 6;
    const int l    = tid & 63;
    const int m    = l & 15;
    const int q    = l >> 4;
    const int tile = blockIdx.x;
    const int b    = blockIdx.y;
    const int n0   = tile * PPB2;

    // A-fragments: af0 = point n0+m, af1 = point n0+16+m.
    // af*[ks] = channels 32ks+8q .. +7 : pair row (4ks+q), one uint4 load.
    const ushort* __restrict__ fb = feat + (size_t)b * 32 * NPAD * 8;
    short8 af0[8], af1[8];
    #pragma unroll
    for (int ks = 0; ks < 8; ++ks) {
        const size_t row = (size_t)(4 * ks + q) * NPAD;
        af0[ks] = *(const short8*)(fb + (row + (n0 + m)) * 8);
        af1[ks] = *(const short8*)(fb + (row + (n0 + 16 + m)) * 8);
    }

    // ---- layer0 (128 <- 256): wave w -> output tiles 2w, 2w+1; 2 M-tiles
    {
        f32x4 a00 = {0.f, 0.f, 0.f, 0.f};   // mtile0 x outtile0
        f32x4 a01 = {0.f, 0.f, 0.f, 0.f};   // mtile0 x outtile1
        f32x4 a10 = {0.f, 0.f, 0.f, 0.f};   // mtile1 x outtile0
        f32x4 a11 = {0.f, 0.f, 0.f, 0.f};   // mtile1 x outtile1
        const ushort* __restrict__ wr0 = W0b + ((size_t)(2 * w) * 16 + m) * 256 + 8 * q;
        const ushort* __restrict__ wr1 = wr0 + 16 * 256;
        #pragma unroll
        for (int ks = 0; ks < 8; ++ks) {
            const short8 w0 = *(const short8*)(wr0 + 32 * ks);
            const short8 w1 = *(const short8*)(wr1 + 32 * ks);
            a00 = __builtin_amdgcn_mfma_f32_16x16x32_bf16(af0[ks], w0, a00, 0, 0, 0);
            a01 = __builtin_amdgcn_mfma_f32_16x16x32_bf16(af0[ks], w1, a01, 0, 0, 0);
            a10 = __builtin_amdgcn_mfma_f32_16x16x32_bf16(af1[ks], w0, a10, 0, 0, 0);
            a11 = __builtin_amdgcn_mfma_f32_16x16x32_bf16(af1[ks], w1, a11, 0, 0, 0);
        }
        const int o0 = (2 * w) * 16 + m, o1 = o0 + 16;
        const float bias0 = b0[o0], bias1 = b0[o1];
        #pragma unroll
        for (int r = 0; r < 4; ++r) {
            float v;
            v = a00[r] + bias0; v = (v > 0.f) ? v : 0.01f * v;
            y0_s[(q * 4 + r) * Y0S + o0] = f2bf(v);
            v = a01[r] + bias1; v = (v > 0.f) ? v : 0.01f * v;
            y0_s[(q * 4 + r) * Y0S + o1] = f2bf(v);
            v = a10[r] + bias0; v = (v > 0.f) ? v : 0.01f * v;
            y0_s[(16 + q * 4 + r) * Y0S + o0] = f2bf(v);
            v = a11[r] + bias1; v = (v > 0.f) ? v : 0.01f * v;
            y0_s[(16 + q * 4 + r) * Y0S + o1] = f2bf(v);
        }
    }
    __syncthreads();

    // ---- layer1 (64 <- [128 y0 | 256 feat]): wave w -> output tile w; 2 M-tiles
    {
        f32x4 acc0 = {0.f, 0.f, 0.f, 0.f};
        f32x4 acc1 = {0.f, 0.f, 0.f, 0.f};
        const ushort* __restrict__ wr = W1b + ((size_t)w * 16 + m) * 384 + 8 * q;
        #pragma unroll
        for (int ks = 0; ks < 4; ++ks) {
            const short8 a0 = *(const short8*)(y0_s + m * Y0S + 32 * ks + 8 * q);
            const short8 a1 = *(const short8*)(y0_s + (16 + m) * Y0S + 32 * ks + 8 * q);
            const short8 bb = *(const short8*)(wr + 32 * ks);
            acc0 = __builtin_amdgcn_mfma_f32_16x16x32_bf16(a0, bb, acc0, 0, 0, 0);
            acc1 = __builtin_amdgcn_mfma_f32_16x16x32_bf16(a1, bb, acc1, 0, 0, 0);
        }
        #pragma unroll
        for (int ks = 4; ks < 12; ++ks) {
            const short8 bb = *(const short8*)(wr + 32 * ks);
            acc0 = __builtin_amdgcn_mfma_f32_16x16x32_bf16(af0[ks - 4], bb, acc0, 0, 0, 0);
            acc1 = __builtin_amdgcn_mfma_f32_16x16x32_bf16(af1[ks - 4], bb, acc1, 0, 0, 0);
        }
        const int o = w * 16 + m;
        const float bias = b1[o];
        #pragma unroll
        for (int r = 0; r < 4; ++r) {
            float v;
            v = acc0[r] + bias; v = (v > 0.f) ? v : 0.01f * v;
            y1_s[(q * 4 + r) * Y1S + o] = f2bf(v);
            v = acc1[r] + bias; v = (v > 0.f) ? v : 0.01f * v;
            y1_s[(16 + q * 4 + r) * Y1S + o] = f2bf(v);
        }
    }
    __syncthreads();

    // ---- layer2 (5 <- [64 y1 | 256 feat]): wave 0 -> mtile0, wave 1 -> mtile1
    if (w < 2) {
        const int mt = w;
        f32x4 acc = {0.f, 0.f, 0.f, 0.f};
        const ushort* __restrict__ wr = W2p + (size_t)m * 320 + 8 * q;
        #pragma unroll
        for (int ks = 0; ks < 2; ++ks) {
            const short8 a  = *(const short8*)(y1_s + (mt * 16 + m) * Y1S + 32 * ks + 8 * q);
            const short8 bb = *(const short8*)(wr + 32 * ks);
            acc = __builtin_amdgcn_mfma_f32_16x16x32_bf16(a, bb, acc, 0, 0, 0);
        }
        #pragma unroll
        for (int ks = 2; ks < 10; ++ks) {
            const short8 bb = *(const short8*)(wr + 32 * ks);
            const short8 a  = mt ? af1[ks - 2] : af0[ks - 2];
            acc = __builtin_amdgcn_mfma_f32_16x16x32_bf16(a, bb, acc, 0, 0, 0);
        }
        if (m < 5) {
            const float bias = b2[m];
            #pragma unroll
            for (int r = 0; r < 4; ++r) {
                const int nn = n0 + mt * 16 + q * 4 + r;
                if (nn < N_) {
                    float v = acc[r] + bias;
                    out[((size_t)b * 5 + m) * N_ + nn] = (v > 0.f) ? v : 0.f;
                }
            }
        }
    }
}

// ---------------- fp32 NCHW fallback (ws too small) ----------------
__global__ __launch_bounds__(256, 4) void maf_fallback_kernel(
    const float* __restrict__ p, const float* __restrict__ cam,
    const float* __restrict__ sfeat,
    const float* __restrict__ W0, const float* __restrict__ b0,
    const float* __restrict__ W1, const float* __restrict__ b1,
    const float* __restrict__ W2, const float* __restrict__ b2,
    float* __restrict__ out)
{
    __shared__ float feat_s[PPB][C_ + 4];
    __shared__ float y0_s[PPB][128 + 4];
    __shared__ float y1_s[PPB][64 + 4];

    const int tid = threadIdx.x;
    const int b   = blockIdx.y;
    const int n0  = blockIdx.x * PPB;
    const float s  = cam[b * 3 + 0];
    const float tx = cam[b * 3 + 1];
    const float ty = cam[b * 3 + 2];
    {
        const int c = tid;
        const float* __restrict__ fb = sfeat + ((size_t)b * C_ + c) * HW_;
        for (int pp = 0; pp < PPB; ++pp) {
            const int n = n0 + pp;
            float val = 0.f;
            if (n < N_) {
                const float px = p[((size_t)b * N_ + n) * 3 + 0];
                const float py = p[((size_t)b * N_ + n) * 3 + 1];
                const float x = (s * (px + tx) + 1.f) * 0.5f * (float)(W_ - 1);
                const float y = (s * (py + ty) + 1.f) * 0.5f * (float)(H_ - 1);
                const float x0f = floorf(x), y0f = floorf(y);
                const float wx1 = x - x0f, wx0 = 1.f - wx1;
                const float wy1 = y - y0f, wy0 = 1.f - wy1;
                const int ix0 = (int)x0f, iy0 = (int)y0f;
                const int ix1 = ix0 + 1,  iy1 = iy0 + 1;
                const bool vx0 = (ix0 >= 0) & (ix0 <= W_ - 1);
                const bool vx1 = (ix1 >= 0) & (ix1 <= W_ - 1);
                const bool vy0 = (iy0 >= 0) & (iy0 <= H_ - 1);
                const bool vy1 = (iy1 >= 0) & (iy1 <= H_ - 1);
                const int cx0 = min(max(ix0, 0), W_ - 1);
                const int cx1 = min(max(ix1, 0), W_ - 1);
                const int cy0 = min(max(iy0, 0), H_ - 1);
                const int cy1 = min(max(iy1, 0), H_ - 1);
                const float w00 = (vx0 & vy0) ? wx0 * wy0 : 0.f;
                const float w10 = (vx1 & vy0) ? wx1 * wy0 : 0.f;
                const float w01 = (vx0 & vy1) ? wx0 * wy1 : 0.f;
                const float w11 = (vx1 & vy1) ? wx1 * wy1 : 0.f;
                val = w00 * fb[cy0 * W_ + cx0] + w10 * fb[cy0 * W_ + cx1]
                    + w01 * fb[cy1 * W_ + cx0] + w11 * fb[cy1 * W_ + cx1];
            }
            feat_s[pp][c] = val;
        }
    }
    __syncthreads();
    {
        const int o = tid & 127, pg = tid >> 7, p0 = pg * 8;
        const float* __restrict__ wr = W0 + (size_t)o * 256;
        float acc[8] = {0, 0, 0, 0, 0, 0, 0, 0};
        for (int k = 0; k < 256; k += 4) {
            const float4 w = *(const float4*)(wr + k);
            for (int i = 0; i < 8; ++i) {
                const float4 f = *(const float4*)&feat_s[p0 + i][k];
                acc[i] += w.x * f.x + w.y * f.y + w.z * f.z + w.w * f.w;
            }
        }
        const float bias = b0[o];
        for (int i = 0; i < 8; ++i) {
            const float v = acc[i] + bias;
            y0_s[p0 + i][o] = (v > 0.f) ? v : 0.01f * v;
        }
    }
    __syncthreads();
    {
        const int o = tid & 63, pg = tid >> 6, p0 = pg * 4;
        const float* __restrict__ wr = W1 + (size_t)o * 384;
        float acc[4] = {0, 0, 0, 0};
        for (int k = 0; k < 128; k += 4) {
            const float4 w = *(const float4*)(wr + k);
            for (int i = 0; i < 4; ++i) {
                const float4 f = *(const float4*)&y0_s[p0 + i][k];
                acc[i] += w.x * f.x + w.y * f.y + w.z * f.z + w.w * f.w;
            }
        }
        for (int k = 0; k < 256; k += 4) {
            const float4 w = *(const float4*)(wr + 128 + k);
            for (int i = 0; i < 4; ++i) {
                const float4 f = *(const float4*)&feat_s[p0 + i][k];
                acc[i] += w.x * f.x + w.y * f.y + w.z * f.z + w.w * f.w;
            }
        }
        const float bias = b1[o];
        for (int i = 0; i < 4; ++i) {
            const float v = acc[i] + bias;
            y1_s[p0 + i][o] = (v > 0.f) ? v : 0.01f * v;
        }
    }
    __syncthreads();
    if (tid < 80) {
        const int o = tid >> 4, pp = tid & 15;
        const float* __restrict__ wr = W2 + (size_t)o * 320;
        float acc = 0.f;
        for (int k = 0; k < 64; k += 4) {
            const float4 w = *(const float4*)(wr + k);
            const float4 f = *(const float4*)&y1_s[pp][k];
            acc += w.x * f.x + w.y * f.y + w.z * f.z + w.w * f.w;
        }
        for (int k = 0; k < 256; k += 4) {
            const float4 w = *(const float4*)(wr + 64 + k);
            const float4 f = *(const float4*)&feat_s[pp][k];
            acc += w.x * f.x + w.y * f.y + w.z * f.z + w.w * f.w;
        }
        const int n = n0 + pp;
        if (n < N_) {
            float v = acc + b2[o];
            out[((size_t)b * 5 + o) * N_ + n] = (v > 0.f) ? v : 0.f;
        }
    }
}

extern "C" void kernel_launch(void* const* d_in, const int* in_sizes, int n_in,
                              void* d_out, int out_size, void* d_ws, size_t ws_size,
                              hipStream_t stream) {
    const float* p     = (const float*)d_in[0];
    const float* cam   = (const float*)d_in[1];
    const float* sfeat = (const float*)d_in[2];
    const float* W0    = (const float*)d_in[3];
    const float* b0    = (const float*)d_in[4];
    const float* W1    = (const float*)d_in[5];
    const float* b1    = (const float*)d_in[6];
    const float* W2    = (const float*)d_in[7];
    const float* b2    = (const float*)d_in[8];
    float* out = (float*)d_out;

    const size_t feat_elems = (size_t)B_ * 32 * NPAD * 8;   // 7,340,032 bf16
    size_t off = feat_elems;
    const size_t w0_off = off; off += 128 * 256;
    const size_t w1_off = off; off += 64 * 384;
    const size_t w2_off = off; off += 16 * 320;
    const size_t need = off * sizeof(ushort);               // ~14.9 MB

    if (ws_size >= need) {
        ushort* feat = (ushort*)d_ws;
        ushort* W0b  = feat + w0_off;
        ushort* W1b  = feat + w1_off;
        ushort* W2p  = feat + w2_off;
        gather_kernel<<<GB_ + 8, 256, 0, stream>>>(
            p, cam, sfeat, W0, W1, W2, feat, W0b, W1b, W2p);
        mlp_kernel<<<dim3(NT2, B_), 256, 0, stream>>>(
            feat, W0b, b0, W1b, b1, W2p, b2, out);
    } else {
        maf_fallback_kernel<<<dim3(NT_, B_), 256, 0, stream>>>(
            p, cam, sfeat, W0, b0, W1, b1, W2, b2, out);
    }
}